// Round 5
// baseline (370.128 us; speedup 1.0000x reference)
//
#include <hip/hip_runtime.h>

#define N_NODES   100000
#define N_EDGES   3200000
#define N_FEAT    128
#define HIDDEN    16
#define N_CLASSES 10
#define N_GRAPHS  64

#define NBUCK     391          // ceil(N_NODES/256), bucket = dst >> 8
#define CAP       9216         // staging capacity per bucket (mean 8192, +11 sigma)
#define BINA_EPB  8192         // edges per block in k_binA (512 thr x 16)
#define BINA_BLOCKS ((N_EDGES + BINA_EPB - 1) / BINA_EPB)   // 391

// Workspace layout (4-byte units):
//   gcur   : [0,        512)       int, per-bucket staging cursor
//   bbase  : [512,      1024)      int, per-bucket CSR base
//   pooled : [1024,     2048)      float [64][16], zeroed each launch
//   dinv   : [2048,     102048)    float
//   off    : [102048,   202080)    int (100001 used)
//   srcs   : [202080,   3402080)   int, CSR by dst
//   stage  : [3402080,  7005536)   int, 391*9216 packed (src<<8 | dst&255)
//   --- overlay onto stage after k_binB (stage dead): ---
//   h1pA   : [3402080,  4202080)   float [N][8]  ch 0-7 of (x@W1)*dinv
//   h1pB   : [4202080,  5002080)   float [N][8]  ch 8-15
//   aggA   : [5002080,  5802080)   float [N][8]  raw layer-1 sums, A half
//   h2pA   : [5802080,  6602080)   float [N][8]  layer-2 feat ch 0-7
//   h2pB   : [6602080,  6802080)   float [N][2]  layer-2 feat ch 8-9
// total 7,005,536 floats = 28.0 MB

__global__ __launch_bounds__(512) void k_ginit(int* __restrict__ gcur,
                                               float* __restrict__ pooled) {
    int t = threadIdx.x;
    if (t < NBUCK) gcur[t] = t * CAP;
    pooled[t] = 0.f;
    pooled[t + 512] = 0.f;
}

// Bin edges by dst>>8 into per-bucket staging. Per block: LDS histogram of
// 8192 edges -> ONE global atomic per bucket reserves a contiguous run
// (~21 edges = 84B) -> LDS-cursor scatter. Edges cached in registers.
__global__ __launch_bounds__(512) void k_binA(const int* __restrict__ src,
                                              const int* __restrict__ dst,
                                              int* __restrict__ gcur,
                                              int* __restrict__ stage) {
    __shared__ int hist[NBUCK];
    __shared__ int curb[NBUCK];
    int tid = threadIdx.x;
    long long base = (long long)blockIdx.x * BINA_EPB;
    for (int t = tid; t < NBUCK; t += 512) hist[t] = 0;
    __syncthreads();
    int se[16], de[16];
#pragma unroll
    for (int i = 0; i < 16; ++i) {
        long long e = base + i * 512 + tid;
        if (e < N_EDGES) {
            se[i] = src[e];
            de[i] = dst[e];
            atomicAdd(&hist[de[i] >> 8], 1);
        } else {
            de[i] = -1;
        }
    }
    __syncthreads();
    for (int t = tid; t < NBUCK; t += 512) {
        int h = hist[t];
        curb[t] = h ? atomicAdd(&gcur[t], h) : 0;
    }
    __syncthreads();
#pragma unroll
    for (int i = 0; i < 16; ++i) {
        if (de[i] >= 0) {
            int b = de[i] >> 8;
            int p = atomicAdd(&curb[b], 1);
            stage[p] = (se[i] << 8) | (de[i] & 255);
        }
    }
}

// Exclusive scan of bucket counts -> per-bucket CSR base.
__global__ __launch_bounds__(512) void k_bscan(const int* __restrict__ gcur,
                                               int* __restrict__ bbase,
                                               int* __restrict__ off) {
    __shared__ int s[512];
    int t = threadIdx.x;
    int c = (t < NBUCK) ? (gcur[t] - t * CAP) : 0;
    s[t] = c;
    __syncthreads();
    for (int o = 1; o < 512; o <<= 1) {
        int a = (t >= o) ? s[t - o] : 0;
        __syncthreads();
        s[t] += a;
        __syncthreads();
    }
    if (t < NBUCK) bbase[t] = s[t] - c;
    if (t == 0) off[N_NODES] = N_EDGES;
}

// One block per bucket: per-node histogram + scan -> off/dinv, then place
// each staged edge at its final CSR slot (all writes within the bucket's
// ~36 KB CSR window -> L2-resident, lines fill).
__global__ __launch_bounds__(256) void k_binB(const int* __restrict__ gcur,
                                              const int* __restrict__ bbase,
                                              const int* __restrict__ stage,
                                              int* __restrict__ off,
                                              float* __restrict__ dinv,
                                              int* __restrict__ srcs) {
    __shared__ int hist[256];
    __shared__ int excl[256];
    int b = blockIdx.x, t = threadIdx.x;
    int cnt   = gcur[b] - b * CAP;
    int sbase = b * CAP;
    int cbase = bbase[b];
    hist[t] = 0;
    __syncthreads();
    for (int i = t; i < cnt; i += 256) {
        int v = stage[sbase + i];
        atomicAdd(&hist[v & 255], 1);
    }
    __syncthreads();
    int c = hist[t];
    excl[t] = c;
    __syncthreads();
    for (int o = 1; o < 256; o <<= 1) {
        int a = (t >= o) ? excl[t - o] : 0;
        __syncthreads();
        excl[t] += a;
        __syncthreads();
    }
    int ex = excl[t] - c;
    int node = b * 256 + t;
    if (node < N_NODES) {
        off[node]  = cbase + ex;
        dinv[node] = rsqrtf((float)c + 1.0f);
    }
    __syncthreads();
    hist[t] = ex;          // reuse as per-node cursor
    __syncthreads();
    for (int i = t; i < cnt; i += 256) {
        int v = stage[sbase + i];
        int p = cbase + atomicAdd(&hist[v & 255], 1);
        srcs[p] = v >> 8;
    }
}

// 16 nodes per block: (x[n] @ W1)[c] * dinv[n], split-stored A/B halves.
__global__ __launch_bounds__(256) void k_gemm1(const float* __restrict__ x,
                                               const float* __restrict__ W1,
                                               const float* __restrict__ dinv,
                                               float* __restrict__ h1pA,
                                               float* __restrict__ h1pB) {
    __shared__ float w[N_FEAT * HIDDEN];   // 8 KB
    __shared__ float xs[16 * N_FEAT];      // 8 KB
    __shared__ float ds[16];
    int tid  = threadIdx.x;
    int base = blockIdx.x * 16;
    if (tid < 16) ds[tid] = dinv[base + tid];
    const float4* w4 = (const float4*)W1;
    float4*       wd = (float4*)w;
    wd[tid]       = w4[tid];
    wd[256 + tid] = w4[256 + tid];
    const float4* x4 = (const float4*)(x + (long long)base * N_FEAT);
    float4*       xd = (float4*)xs;
    xd[tid]       = x4[tid];
    xd[256 + tid] = x4[256 + tid];
    __syncthreads();
    int n = tid >> 4, c = tid & 15;
    const float* xr = &xs[n * N_FEAT];
    float acc = 0.f;
#pragma unroll
    for (int k = 0; k < N_FEAT; ++k) acc += xr[k] * w[k * HIDDEN + c];
    float v = acc * ds[n];
    int nn = base + n;
    if (c < 8) h1pA[nn * 8 + c] = v;
    else       h1pB[nn * 8 + (c - 8)] = v;
}

// CSR gather over h1pA (3.2MB table, L2-resident). 8 lanes/node, 32 nodes/blk.
__global__ __launch_bounds__(256) void k_agg1A(const int* __restrict__ off,
                                               const int* __restrict__ srcs,
                                               const float* __restrict__ h1pA,
                                               float* __restrict__ aggA) {
    int tid = threadIdx.x;
    int nl = tid >> 3, c = tid & 7;
    int n  = blockIdx.x * 32 + nl;
    int beg = off[n], end = off[n + 1];
    float a0 = h1pA[n * 8 + c];            // self-loop
    float a1 = 0.f, a2 = 0.f, a3 = 0.f;
    int j = beg;
    for (; j + 3 < end; j += 4) {
        int s0 = __builtin_nontemporal_load(&srcs[j]);
        int s1 = __builtin_nontemporal_load(&srcs[j + 1]);
        int s2 = __builtin_nontemporal_load(&srcs[j + 2]);
        int s3 = __builtin_nontemporal_load(&srcs[j + 3]);
        a0 += h1pA[s0 * 8 + c];
        a1 += h1pA[s1 * 8 + c];
        a2 += h1pA[s2 * 8 + c];
        a3 += h1pA[s3 * 8 + c];
    }
    for (; j < end; ++j) a0 += h1pA[srcs[j] * 8 + c];
    __builtin_nontemporal_store((a0 + a1) + (a2 + a3), &aggA[n * 8 + c]);
}

// CSR gather over h1pB + combine aggA + dinv + bias + ReLU + @W2 -> h2pA/h2pB.
__global__ __launch_bounds__(256) void k_agg1B(const int* __restrict__ off,
                                               const int* __restrict__ srcs,
                                               const float* __restrict__ dinv,
                                               const float* __restrict__ h1pB,
                                               const float* __restrict__ aggA,
                                               const float* __restrict__ b1,
                                               const float* __restrict__ W2,
                                               float* __restrict__ h2pA,
                                               float* __restrict__ h2pB) {
    __shared__ float r_s[32][17];
    __shared__ float w2s[HIDDEN * N_CLASSES];
    int tid = threadIdx.x;
    if (tid < HIDDEN * N_CLASSES) w2s[tid] = W2[tid];
    int nl = tid >> 3, c = tid & 7;
    int n  = blockIdx.x * 32 + nl;
    int beg = off[n], end = off[n + 1];
    float a0 = h1pB[n * 8 + c];            // self-loop
    float a1 = 0.f, a2 = 0.f, a3 = 0.f;
    int j = beg;
    for (; j + 3 < end; j += 4) {
        int s0 = __builtin_nontemporal_load(&srcs[j]);
        int s1 = __builtin_nontemporal_load(&srcs[j + 1]);
        int s2 = __builtin_nontemporal_load(&srcs[j + 2]);
        int s3 = __builtin_nontemporal_load(&srcs[j + 3]);
        a0 += h1pB[s0 * 8 + c];
        a1 += h1pB[s1 * 8 + c];
        a2 += h1pB[s2 * 8 + c];
        a3 += h1pB[s3 * 8 + c];
    }
    for (; j < end; ++j) a0 += h1pB[srcs[j] * 8 + c];
    float sb = (a0 + a1) + (a2 + a3);
    float sa = __builtin_nontemporal_load(&aggA[n * 8 + c]);
    float dn = dinv[n];
    r_s[nl][c]     = fmaxf(dn * sa + b1[c], 0.f);
    r_s[nl][c + 8] = fmaxf(dn * sb + b1[c + 8], 0.f);
    __syncthreads();
    float o = 0.f;
#pragma unroll
    for (int k = 0; k < HIDDEN; ++k) o += r_s[nl][k] * w2s[k * N_CLASSES + c];
    __builtin_nontemporal_store(dn * o, &h2pA[n * 8 + c]);
    if (c < 2) {
        float o2 = 0.f;
#pragma unroll
        for (int k = 0; k < HIDDEN; ++k) o2 += r_s[nl][k] * w2s[k * N_CLASSES + 8 + c];
        __builtin_nontemporal_store(dn * o2, &h2pB[n * 2 + c]);
    }
}

// CSR gather over h2pA (3.2MB, L2-resident) + fused pooling of ch 0-7.
__global__ __launch_bounds__(256) void k_agg2A(const int* __restrict__ off,
                                               const int* __restrict__ srcs,
                                               const float* __restrict__ dinv,
                                               const float* __restrict__ h2pA,
                                               const int* __restrict__ batch,
                                               float* __restrict__ pooled) {
    __shared__ float red[32][9];
    int tid = threadIdx.x;
    int nl = tid >> 3, c = tid & 7;
    int nbase = blockIdx.x * 32;
    int n  = nbase + nl;
    int beg = off[n], end = off[n + 1];
    float a0 = h2pA[n * 8 + c];            // self-loop
    float a1 = 0.f, a2 = 0.f, a3 = 0.f;
    int j = beg;
    for (; j + 3 < end; j += 4) {
        int s0 = __builtin_nontemporal_load(&srcs[j]);
        int s1 = __builtin_nontemporal_load(&srcs[j + 1]);
        int s2 = __builtin_nontemporal_load(&srcs[j + 2]);
        int s3 = __builtin_nontemporal_load(&srcs[j + 3]);
        a0 += h2pA[s0 * 8 + c];
        a1 += h2pA[s1 * 8 + c];
        a2 += h2pA[s2 * 8 + c];
        a3 += h2pA[s3 * 8 + c];
    }
    for (; j < end; ++j) a0 += h2pA[srcs[j] * 8 + c];
    float o = dinv[n] * ((a0 + a1) + (a2 + a3));

    int g0 = batch[nbase];
    int gL = batch[nbase + 31];
    if (g0 == gL) {                  // uniform: whole block in one graph
        red[nl][c] = o;
        __syncthreads();
#pragma unroll
        for (int s = 16; s > 0; s >>= 1) {
            if (nl < s) red[nl][c] += red[nl + s][c];
            __syncthreads();
        }
        if (tid < 8) atomicAdd(&pooled[g0 * 16 + tid], red[0][tid]);
    } else {                         // boundary block (rare)
        atomicAdd(&pooled[batch[n] * 16 + c], o);
    }
}

// CSR gather over h2pB (0.8MB) + fused pooling of ch 8-9. 2 lanes/node.
__global__ __launch_bounds__(256) void k_agg2B(const int* __restrict__ off,
                                               const int* __restrict__ srcs,
                                               const float* __restrict__ dinv,
                                               const float* __restrict__ h2pB,
                                               const int* __restrict__ batch,
                                               float* __restrict__ pooled) {
    __shared__ float red[128][3];
    int tid = threadIdx.x;
    int nl = tid >> 1, c = tid & 1;
    int nbase = blockIdx.x * 128;
    int n  = nbase + nl;
    float o = 0.f;
    if (n < N_NODES) {
        int beg = off[n], end = off[n + 1];
        float a0 = h2pB[n * 2 + c];        // self-loop
        float a1 = 0.f, a2 = 0.f, a3 = 0.f;
        int j = beg;
        for (; j + 3 < end; j += 4) {
            int s0 = __builtin_nontemporal_load(&srcs[j]);
            int s1 = __builtin_nontemporal_load(&srcs[j + 1]);
            int s2 = __builtin_nontemporal_load(&srcs[j + 2]);
            int s3 = __builtin_nontemporal_load(&srcs[j + 3]);
            a0 += h2pB[s0 * 2 + c];
            a1 += h2pB[s1 * 2 + c];
            a2 += h2pB[s2 * 2 + c];
            a3 += h2pB[s3 * 2 + c];
        }
        for (; j < end; ++j) a0 += h2pB[srcs[j] * 2 + c];
        o = dinv[n] * ((a0 + a1) + (a2 + a3));
    }
    int nLast = nbase + 127;
    if (nLast >= N_NODES) nLast = N_NODES - 1;
    int g0 = batch[nbase];
    int gL = batch[nLast];
    if (g0 == gL) {
        red[nl][c] = o;
        __syncthreads();
#pragma unroll
        for (int s = 64; s > 0; s >>= 1) {
            if (nl < s) red[nl][c] += red[nl + s][c];
            __syncthreads();
        }
        if (tid < 2) atomicAdd(&pooled[g0 * 16 + 8 + tid], red[0][tid]);
    } else {
        if (n < N_NODES) atomicAdd(&pooled[batch[n] * 16 + 8 + c], o);
    }
}

// one block, one thread per graph: counts via binary search on sorted batch,
// mean + b2, log_softmax -> out.
__global__ __launch_bounds__(64) void k_final(const float* __restrict__ pooled,
                                              const float* __restrict__ b2,
                                              const int* __restrict__ batch,
                                              float* __restrict__ out) {
    int g = threadIdx.x;
    if (g >= N_GRAPHS) return;
    int lo = 0, hi = N_NODES;
    while (lo < hi) { int m = (lo + hi) >> 1; if (batch[m] < g) lo = m + 1; else hi = m; }
    int start = lo;
    lo = 0; hi = N_NODES;
    while (lo < hi) { int m = (lo + hi) >> 1; if (batch[m] < g + 1) lo = m + 1; else hi = m; }
    int cnt = lo - start;

    float v[N_CLASSES];
    if (cnt > 0) {
        float inv = 1.f / (float)cnt;
#pragma unroll
        for (int j = 0; j < N_CLASSES; ++j) v[j] = pooled[g * 16 + j] * inv + b2[j];
    } else {
#pragma unroll
        for (int j = 0; j < N_CLASSES; ++j) v[j] = 0.f;
    }
    float m = v[0];
#pragma unroll
    for (int j = 1; j < N_CLASSES; ++j) m = fmaxf(m, v[j]);
    float l = 0.f;
#pragma unroll
    for (int j = 0; j < N_CLASSES; ++j) l += expf(v[j] - m);
    l = logf(l);
#pragma unroll
    for (int j = 0; j < N_CLASSES; ++j) out[g * N_CLASSES + j] = v[j] - m - l;
}

extern "C" void kernel_launch(void* const* d_in, const int* in_sizes, int n_in,
                              void* d_out, int out_size, void* d_ws, size_t ws_size,
                              hipStream_t stream) {
    const float* x     = (const float*)d_in[0];
    const int*   edge  = (const int*)d_in[1];   // [2, E]
    const int*   batch = (const int*)d_in[2];
    const float* W1    = (const float*)d_in[3];
    const float* b1    = (const float*)d_in[4];
    const float* W2    = (const float*)d_in[5];
    const float* b2    = (const float*)d_in[6];
    float* out = (float*)d_out;
    float* ws  = (float*)d_ws;

    int*   gcur   = (int*)ws;                  // [0, 512)
    int*   bbase  = (int*)(ws + 512);          // [512, 1024)
    float* pooled = ws + 1024;                 // [1024, 2048)
    float* dinv   = ws + 2048;                 // [2048, 102048)
    int*   off    = (int*)(ws + 102048);       // 100001 used
    int*   srcs   = (int*)(ws + 202080);       // 3.2M
    int*   stage  = (int*)(ws + 3402080);      // 391*9216
    float* h1pA   = ws + 3402080;              // overlay (stage dead after binB)
    float* h1pB   = ws + 4202080;
    float* aggA   = ws + 5002080;
    float* h2pA   = ws + 5802080;
    float* h2pB   = ws + 6602080;

    const int* srcp = edge;
    const int* dstp = edge + N_EDGES;

    k_ginit<<<1, 512, 0, stream>>>(gcur, pooled);
    k_binA<<<BINA_BLOCKS, 512, 0, stream>>>(srcp, dstp, gcur, stage);
    k_bscan<<<1, 512, 0, stream>>>(gcur, bbase, off);
    k_binB<<<NBUCK, 256, 0, stream>>>(gcur, bbase, stage, off, dinv, srcs);
    k_gemm1<<<N_NODES / 16, 256, 0, stream>>>(x, W1, dinv, h1pA, h1pB);
    k_agg1A<<<N_NODES / 32, 256, 0, stream>>>(off, srcs, h1pA, aggA);
    k_agg1B<<<N_NODES / 32, 256, 0, stream>>>(off, srcs, dinv, h1pB, aggA, b1, W2, h2pA, h2pB);
    k_agg2A<<<N_NODES / 32, 256, 0, stream>>>(off, srcs, dinv, h2pA, batch, pooled);
    k_agg2B<<<(N_NODES + 127) / 128, 256, 0, stream>>>(off, srcs, dinv, h2pB, batch, pooled);
    k_final<<<1, 64, 0, stream>>>(pooled, b2, batch, out);
}

// Round 6
// 283.078 us; speedup vs baseline: 1.3075x; 1.3075x over previous
//
#include <hip/hip_runtime.h>

#define N_NODES   100000
#define N_EDGES   3200000
#define N_FEAT    128
#define HIDDEN    16
#define N_CLASSES 10
#define N_GRAPHS  64

#define NBUCK     391          // ceil(N_NODES/256), bucket = dst >> 8
#define CAP       9216         // staging capacity per bucket (mean 8192, +11 sigma)
#define BINA_EPB  16384        // edges per block in k_binA (1024 thr x 16)
#define BINA_BLOCKS ((N_EDGES + BINA_EPB - 1) / BINA_EPB)   // 196

// Workspace layout (4-byte units):
//   gcur   : [0,        512)       int, per-bucket staging cursor
//   bbase  : [512,      1024)      int, per-bucket CSR base
//   pooled : [1024,     2048)      float [64][16], zeroed each launch
//   dinv   : [2048,     102048)    float
//   off    : [102048,   202080)    int (100001 used)
//   srcs   : [202080,   3402080)   int, CSR by dst
//   stage  : [3402080,  7005536)   int, 391*9216 packed (src<<8 | dst&255)
//   h1p    : [3402080,  5002080)   float [N][16] (overlays stage; stage dead)
//   h2p    : [5002080,  6602080)   float [N][16] (c>=10 zero)
// total ~28.0 MB

__global__ __launch_bounds__(512) void k_ginit(int* __restrict__ gcur,
                                               float* __restrict__ pooled) {
    int t = threadIdx.x;
    if (t < NBUCK) gcur[t] = t * CAP;
    pooled[t] = 0.f;
    pooled[t + 512] = 0.f;
}

// Bin edges by dst>>8 into per-bucket staging. Per block: LDS histogram of
// 16384 edges -> ONE global atomic per bucket reserves a contiguous run
// (~42 edges = 168B) -> LDS-cursor scatter. Edges cached in registers.
__global__ __launch_bounds__(1024) void k_binA(const int* __restrict__ src,
                                               const int* __restrict__ dst,
                                               int* __restrict__ gcur,
                                               int* __restrict__ stage) {
    __shared__ int hist[NBUCK];
    __shared__ int curb[NBUCK];
    int tid = threadIdx.x;
    long long base = (long long)blockIdx.x * BINA_EPB;
    for (int t = tid; t < NBUCK; t += 1024) hist[t] = 0;
    __syncthreads();
    int se[16], de[16];
#pragma unroll
    for (int i = 0; i < 16; ++i) {
        long long e = base + i * 1024 + tid;
        if (e < N_EDGES) {
            se[i] = src[e];
            de[i] = dst[e];
            atomicAdd(&hist[de[i] >> 8], 1);
        } else {
            de[i] = -1;
        }
    }
    __syncthreads();
    for (int t = tid; t < NBUCK; t += 1024) {
        int h = hist[t];
        curb[t] = h ? atomicAdd(&gcur[t], h) : 0;
    }
    __syncthreads();
#pragma unroll
    for (int i = 0; i < 16; ++i) {
        if (de[i] >= 0) {
            int b = de[i] >> 8;
            int p = atomicAdd(&curb[b], 1);
            stage[p] = (se[i] << 8) | (de[i] & 255);
        }
    }
}

// Exclusive scan of bucket counts -> per-bucket CSR base.
__global__ __launch_bounds__(512) void k_bscan(const int* __restrict__ gcur,
                                               int* __restrict__ bbase,
                                               int* __restrict__ off) {
    __shared__ int s[512];
    int t = threadIdx.x;
    int c = (t < NBUCK) ? (gcur[t] - t * CAP) : 0;
    s[t] = c;
    __syncthreads();
    for (int o = 1; o < 512; o <<= 1) {
        int a = (t >= o) ? s[t - o] : 0;
        __syncthreads();
        s[t] += a;
        __syncthreads();
    }
    if (t < NBUCK) bbase[t] = s[t] - c;
    if (t == 0) off[N_NODES] = N_EDGES;
}

// One block per bucket: per-node histogram + scan -> off/dinv, then place
// each staged edge at its final CSR slot (all writes within the bucket's
// ~36 KB CSR window -> L2-resident, lines fill).
__global__ __launch_bounds__(256) void k_binB(const int* __restrict__ gcur,
                                              const int* __restrict__ bbase,
                                              const int* __restrict__ stage,
                                              int* __restrict__ off,
                                              float* __restrict__ dinv,
                                              int* __restrict__ srcs) {
    __shared__ int hist[256];
    __shared__ int excl[256];
    int b = blockIdx.x, t = threadIdx.x;
    int cnt   = gcur[b] - b * CAP;
    int sbase = b * CAP;
    int cbase = bbase[b];
    hist[t] = 0;
    __syncthreads();
    for (int i = t; i < cnt; i += 256) {
        int v = stage[sbase + i];
        atomicAdd(&hist[v & 255], 1);
    }
    __syncthreads();
    int c = hist[t];
    excl[t] = c;
    __syncthreads();
    for (int o = 1; o < 256; o <<= 1) {
        int a = (t >= o) ? excl[t - o] : 0;
        __syncthreads();
        excl[t] += a;
        __syncthreads();
    }
    int ex = excl[t] - c;
    int node = b * 256 + t;
    if (node < N_NODES) {
        off[node]  = cbase + ex;
        dinv[node] = rsqrtf((float)c + 1.0f);
    }
    __syncthreads();
    hist[t] = ex;          // reuse as per-node cursor
    __syncthreads();
    for (int i = t; i < cnt; i += 256) {
        int v = stage[sbase + i];
        int p = cbase + atomicAdd(&hist[v & 255], 1);
        srcs[p] = v >> 8;
    }
}

// 16 nodes per block: h1p[n][c] = (x[n] @ W1)[c] * dinv[n]
__global__ __launch_bounds__(256) void k_gemm1(const float* __restrict__ x,
                                               const float* __restrict__ W1,
                                               const float* __restrict__ dinv,
                                               float* __restrict__ h1p) {
    __shared__ float w[N_FEAT * HIDDEN];   // 8 KB
    __shared__ float xs[16 * N_FEAT];      // 8 KB
    __shared__ float ds[16];
    int tid  = threadIdx.x;
    int base = blockIdx.x * 16;
    if (tid < 16) ds[tid] = dinv[base + tid];
    const float4* w4 = (const float4*)W1;
    float4*       wd = (float4*)w;
    wd[tid]       = w4[tid];
    wd[256 + tid] = w4[256 + tid];
    const float4* x4 = (const float4*)(x + (long long)base * N_FEAT);
    float4*       xd = (float4*)xs;
    xd[tid]       = x4[tid];
    xd[256 + tid] = x4[256 + tid];
    __syncthreads();
    int n = tid >> 4, c = tid & 15;
    const float* xr = &xs[n * N_FEAT];
    float acc = 0.f;
#pragma unroll
    for (int k = 0; k < N_FEAT; ++k) acc += xr[k] * w[k * HIDDEN + c];
    h1p[(base + n) * HIDDEN + c] = acc * ds[n];
}

// Fused: CSR gather of layer-1 aggregation + bias + ReLU + (@W2) + dinv scale.
// 16 lanes (channels) per node, 16 nodes per block. 8-deep unroll: 8
// independent gathers in flight per lane (latency-bound -> MLP is the lever).
__global__ __launch_bounds__(256) void k_agg1(const int* __restrict__ off,
                                              const int* __restrict__ srcs,
                                              const float* __restrict__ dinv,
                                              const float* __restrict__ h1p,
                                              const float* __restrict__ b1,
                                              const float* __restrict__ W2,
                                              float* __restrict__ h2p) {
    __shared__ float r_s[16][17];
    __shared__ float w2s[HIDDEN * N_CLASSES];
    int tid = threadIdx.x;
    if (tid < HIDDEN * N_CLASSES) w2s[tid] = W2[tid];
    int nl = tid >> 4, c = tid & 15;
    int n  = blockIdx.x * 16 + nl;
    int beg = off[n], end = off[n + 1];
    float a0 = h1p[n * 16 + c];            // self-loop
    float a1 = 0.f, a2 = 0.f, a3 = 0.f;
    float a4 = 0.f, a5 = 0.f, a6 = 0.f, a7 = 0.f;
    int j = beg;
    for (; j + 7 < end; j += 8) {
        int s0 = __builtin_nontemporal_load(&srcs[j]);
        int s1 = __builtin_nontemporal_load(&srcs[j + 1]);
        int s2 = __builtin_nontemporal_load(&srcs[j + 2]);
        int s3 = __builtin_nontemporal_load(&srcs[j + 3]);
        int s4 = __builtin_nontemporal_load(&srcs[j + 4]);
        int s5 = __builtin_nontemporal_load(&srcs[j + 5]);
        int s6 = __builtin_nontemporal_load(&srcs[j + 6]);
        int s7 = __builtin_nontemporal_load(&srcs[j + 7]);
        a0 += h1p[s0 * 16 + c];
        a1 += h1p[s1 * 16 + c];
        a2 += h1p[s2 * 16 + c];
        a3 += h1p[s3 * 16 + c];
        a4 += h1p[s4 * 16 + c];
        a5 += h1p[s5 * 16 + c];
        a6 += h1p[s6 * 16 + c];
        a7 += h1p[s7 * 16 + c];
    }
    for (; j + 3 < end; j += 4) {
        int s0 = __builtin_nontemporal_load(&srcs[j]);
        int s1 = __builtin_nontemporal_load(&srcs[j + 1]);
        int s2 = __builtin_nontemporal_load(&srcs[j + 2]);
        int s3 = __builtin_nontemporal_load(&srcs[j + 3]);
        a0 += h1p[s0 * 16 + c];
        a1 += h1p[s1 * 16 + c];
        a2 += h1p[s2 * 16 + c];
        a3 += h1p[s3 * 16 + c];
    }
    for (; j < end; ++j) a0 += h1p[srcs[j] * 16 + c];
    float acc = (((a0 + a1) + (a2 + a3)) + ((a4 + a5) + (a6 + a7)));
    float dn  = dinv[n];
    r_s[nl][c] = fmaxf(dn * acc + b1[c], 0.f);
    __syncthreads();
    if (c < N_CLASSES) {
        float o = 0.f;
#pragma unroll
        for (int k = 0; k < HIDDEN; ++k) o += r_s[nl][k] * w2s[k * N_CLASSES + c];
        h2p[n * 16 + c] = dn * o;
    } else {
        h2p[n * 16 + c] = 0.f;
    }
}

// CSR gather of layer-2 aggregation, fused with graph pooling. 8-deep unroll.
__global__ __launch_bounds__(256) void k_agg2p(const int* __restrict__ off,
                                               const int* __restrict__ srcs,
                                               const float* __restrict__ dinv,
                                               const float* __restrict__ h2p,
                                               const int* __restrict__ batch,
                                               float* __restrict__ pooled) {
    __shared__ float red[16][17];
    int tid = threadIdx.x;
    int nl = tid >> 4, c = tid & 15;
    int nbase = blockIdx.x * 16;
    int n  = nbase + nl;
    int beg = off[n], end = off[n + 1];
    float a0 = h2p[n * 16 + c];            // self-loop
    float a1 = 0.f, a2 = 0.f, a3 = 0.f;
    float a4 = 0.f, a5 = 0.f, a6 = 0.f, a7 = 0.f;
    int j = beg;
    for (; j + 7 < end; j += 8) {
        int s0 = __builtin_nontemporal_load(&srcs[j]);
        int s1 = __builtin_nontemporal_load(&srcs[j + 1]);
        int s2 = __builtin_nontemporal_load(&srcs[j + 2]);
        int s3 = __builtin_nontemporal_load(&srcs[j + 3]);
        int s4 = __builtin_nontemporal_load(&srcs[j + 4]);
        int s5 = __builtin_nontemporal_load(&srcs[j + 5]);
        int s6 = __builtin_nontemporal_load(&srcs[j + 6]);
        int s7 = __builtin_nontemporal_load(&srcs[j + 7]);
        a0 += h2p[s0 * 16 + c];
        a1 += h2p[s1 * 16 + c];
        a2 += h2p[s2 * 16 + c];
        a3 += h2p[s3 * 16 + c];
        a4 += h2p[s4 * 16 + c];
        a5 += h2p[s5 * 16 + c];
        a6 += h2p[s6 * 16 + c];
        a7 += h2p[s7 * 16 + c];
    }
    for (; j + 3 < end; j += 4) {
        int s0 = __builtin_nontemporal_load(&srcs[j]);
        int s1 = __builtin_nontemporal_load(&srcs[j + 1]);
        int s2 = __builtin_nontemporal_load(&srcs[j + 2]);
        int s3 = __builtin_nontemporal_load(&srcs[j + 3]);
        a0 += h2p[s0 * 16 + c];
        a1 += h2p[s1 * 16 + c];
        a2 += h2p[s2 * 16 + c];
        a3 += h2p[s3 * 16 + c];
    }
    for (; j < end; ++j) a0 += h2p[srcs[j] * 16 + c];
    float o = dinv[n] * (((a0 + a1) + (a2 + a3)) + ((a4 + a5) + (a6 + a7)));

    int g0  = batch[nbase];
    int g15 = batch[nbase + 15];
    if (g0 == g15) {                 // uniform branch: whole block one graph
        red[nl][c] = o;
        __syncthreads();
#pragma unroll
        for (int s = 8; s > 0; s >>= 1) {
            if (nl < s) red[nl][c] += red[nl + s][c];
            __syncthreads();
        }
        if (tid < N_CLASSES) atomicAdd(&pooled[g0 * 16 + tid], red[0][tid]);
    } else {                         // graph boundary inside block (rare)
        if (c < N_CLASSES) atomicAdd(&pooled[batch[n] * 16 + c], o);
    }
}

// one block, one thread per graph: counts via binary search on sorted batch,
// mean + b2, log_softmax -> out.
__global__ __launch_bounds__(64) void k_final(const float* __restrict__ pooled,
                                              const float* __restrict__ b2,
                                              const int* __restrict__ batch,
                                              float* __restrict__ out) {
    int g = threadIdx.x;
    if (g >= N_GRAPHS) return;
    int lo = 0, hi = N_NODES;
    while (lo < hi) { int m = (lo + hi) >> 1; if (batch[m] < g) lo = m + 1; else hi = m; }
    int start = lo;
    lo = 0; hi = N_NODES;
    while (lo < hi) { int m = (lo + hi) >> 1; if (batch[m] < g + 1) lo = m + 1; else hi = m; }
    int cnt = lo - start;

    float v[N_CLASSES];
    if (cnt > 0) {
        float inv = 1.f / (float)cnt;
#pragma unroll
        for (int j = 0; j < N_CLASSES; ++j) v[j] = pooled[g * 16 + j] * inv + b2[j];
    } else {
#pragma unroll
        for (int j = 0; j < N_CLASSES; ++j) v[j] = 0.f;
    }
    float m = v[0];
#pragma unroll
    for (int j = 1; j < N_CLASSES; ++j) m = fmaxf(m, v[j]);
    float l = 0.f;
#pragma unroll
    for (int j = 0; j < N_CLASSES; ++j) l += expf(v[j] - m);
    l = logf(l);
#pragma unroll
    for (int j = 0; j < N_CLASSES; ++j) out[g * N_CLASSES + j] = v[j] - m - l;
}

extern "C" void kernel_launch(void* const* d_in, const int* in_sizes, int n_in,
                              void* d_out, int out_size, void* d_ws, size_t ws_size,
                              hipStream_t stream) {
    const float* x     = (const float*)d_in[0];
    const int*   edge  = (const int*)d_in[1];   // [2, E]
    const int*   batch = (const int*)d_in[2];
    const float* W1    = (const float*)d_in[3];
    const float* b1    = (const float*)d_in[4];
    const float* W2    = (const float*)d_in[5];
    const float* b2    = (const float*)d_in[6];
    float* out = (float*)d_out;
    float* ws  = (float*)d_ws;

    int*   gcur   = (int*)ws;                  // [0, 512)
    int*   bbase  = (int*)(ws + 512);          // [512, 1024)
    float* pooled = ws + 1024;                 // [1024, 2048)
    float* dinv   = ws + 2048;                 // [2048, 102048)
    int*   off    = (int*)(ws + 102048);       // 100001 used
    int*   srcs   = (int*)(ws + 202080);       // 3.2M
    int*   stage  = (int*)(ws + 3402080);      // 391*9216
    float* h1p    = ws + 3402080;              // overlays stage (dead after binB)
    float* h2p    = ws + 5002080;

    const int* srcp = edge;
    const int* dstp = edge + N_EDGES;

    k_ginit<<<1, 512, 0, stream>>>(gcur, pooled);
    k_binA<<<BINA_BLOCKS, 1024, 0, stream>>>(srcp, dstp, gcur, stage);
    k_bscan<<<1, 512, 0, stream>>>(gcur, bbase, off);
    k_binB<<<NBUCK, 256, 0, stream>>>(gcur, bbase, stage, off, dinv, srcs);
    k_gemm1<<<N_NODES / 16, 256, 0, stream>>>(x, W1, dinv, h1p);
    k_agg1<<<N_NODES / 16, 256, 0, stream>>>(off, srcs, dinv, h1p, b1, W2, h2p);
    k_agg2p<<<N_NODES / 16, 256, 0, stream>>>(off, srcs, dinv, h2p, batch, pooled);
    k_final<<<1, 64, 0, stream>>>(pooled, b2, batch, out);
}

// Round 7
// 269.583 us; speedup vs baseline: 1.3730x; 1.0501x over previous
//
#include <hip/hip_runtime.h>
#include <hip/hip_fp16.h>

#define N_NODES   100000
#define N_EDGES   3200000
#define N_FEAT    128
#define HIDDEN    16
#define N_CLASSES 10
#define N_GRAPHS  64

#define NBUCK     391          // ceil(N_NODES/256), bucket = dst >> 8
#define CAP       9216         // staging capacity per bucket (mean 8192, +11 sigma)
#define BINA_EPB  16384        // edges per block in k_binA (1024 thr x 16)
#define BINA_BLOCKS ((N_EDGES + BINA_EPB - 1) / BINA_EPB)   // 196

// Workspace layout (4-byte units):
//   gcur   : [0,        512)       int, per-bucket staging cursor
//   bbase  : [512,      1024)      int, per-bucket CSR base
//   pooled : [1024,     2048)      float [64][16], zeroed each launch
//   dinv   : [2048,     102048)    float
//   off    : [102048,   202080)    int (100001 used)
//   srcs   : [202080,   3402080)   int, CSR by dst
//   stage  : [3402080,  7005536)   int, 391*9216 packed (src<<8 | dst&255)
//   h1h    : [3402080,  4202080)   __half [N][16] (x@W1)*dinv  (overlays stage)
//   h2h    : [4202080,  5002080)   __half [N][16] layer-2 feats, c>=10 zero
// total ~28.0 MB

__global__ __launch_bounds__(512) void k_ginit(int* __restrict__ gcur,
                                               float* __restrict__ pooled) {
    int t = threadIdx.x;
    if (t < NBUCK) gcur[t] = t * CAP;
    pooled[t] = 0.f;
    pooled[t + 512] = 0.f;
}

// Bin edges by dst>>8 into per-bucket staging. Per block: LDS histogram of
// 16384 edges -> ONE global atomic per bucket reserves a contiguous run
// (~42 edges = 168B) -> LDS-cursor scatter. Edges cached in registers.
__global__ __launch_bounds__(1024) void k_binA(const int* __restrict__ src,
                                               const int* __restrict__ dst,
                                               int* __restrict__ gcur,
                                               int* __restrict__ stage) {
    __shared__ int hist[NBUCK];
    __shared__ int curb[NBUCK];
    int tid = threadIdx.x;
    long long base = (long long)blockIdx.x * BINA_EPB;
    for (int t = tid; t < NBUCK; t += 1024) hist[t] = 0;
    __syncthreads();
    int se[16], de[16];
#pragma unroll
    for (int i = 0; i < 16; ++i) {
        long long e = base + i * 1024 + tid;
        if (e < N_EDGES) {
            se[i] = src[e];
            de[i] = dst[e];
            atomicAdd(&hist[de[i] >> 8], 1);
        } else {
            de[i] = -1;
        }
    }
    __syncthreads();
    for (int t = tid; t < NBUCK; t += 1024) {
        int h = hist[t];
        curb[t] = h ? atomicAdd(&gcur[t], h) : 0;
    }
    __syncthreads();
#pragma unroll
    for (int i = 0; i < 16; ++i) {
        if (de[i] >= 0) {
            int b = de[i] >> 8;
            int p = atomicAdd(&curb[b], 1);
            stage[p] = (se[i] << 8) | (de[i] & 255);
        }
    }
}

// Exclusive scan of bucket counts -> per-bucket CSR base.
__global__ __launch_bounds__(512) void k_bscan(const int* __restrict__ gcur,
                                               int* __restrict__ bbase,
                                               int* __restrict__ off) {
    __shared__ int s[512];
    int t = threadIdx.x;
    int c = (t < NBUCK) ? (gcur[t] - t * CAP) : 0;
    s[t] = c;
    __syncthreads();
    for (int o = 1; o < 512; o <<= 1) {
        int a = (t >= o) ? s[t - o] : 0;
        __syncthreads();
        s[t] += a;
        __syncthreads();
    }
    if (t < NBUCK) bbase[t] = s[t] - c;
    if (t == 0) off[N_NODES] = N_EDGES;
}

// One block per bucket: per-node histogram + scan -> off/dinv, then place
// each staged edge at its final CSR slot.
__global__ __launch_bounds__(256) void k_binB(const int* __restrict__ gcur,
                                              const int* __restrict__ bbase,
                                              const int* __restrict__ stage,
                                              int* __restrict__ off,
                                              float* __restrict__ dinv,
                                              int* __restrict__ srcs) {
    __shared__ int hist[256];
    __shared__ int excl[256];
    int b = blockIdx.x, t = threadIdx.x;
    int cnt   = gcur[b] - b * CAP;
    int sbase = b * CAP;
    int cbase = bbase[b];
    hist[t] = 0;
    __syncthreads();
    for (int i = t; i < cnt; i += 256) {
        int v = stage[sbase + i];
        atomicAdd(&hist[v & 255], 1);
    }
    __syncthreads();
    int c = hist[t];
    excl[t] = c;
    __syncthreads();
    for (int o = 1; o < 256; o <<= 1) {
        int a = (t >= o) ? excl[t - o] : 0;
        __syncthreads();
        excl[t] += a;
        __syncthreads();
    }
    int ex = excl[t] - c;
    int node = b * 256 + t;
    if (node < N_NODES) {
        off[node]  = cbase + ex;
        dinv[node] = rsqrtf((float)c + 1.0f);
    }
    __syncthreads();
    hist[t] = ex;          // reuse as per-node cursor
    __syncthreads();
    for (int i = t; i < cnt; i += 256) {
        int v = stage[sbase + i];
        int p = cbase + atomicAdd(&hist[v & 255], 1);
        srcs[p] = v >> 8;
    }
}

// 16 nodes per block: h1h[n][c] = fp16((x[n] @ W1)[c] * dinv[n])
__global__ __launch_bounds__(256) void k_gemm1(const float* __restrict__ x,
                                               const float* __restrict__ W1,
                                               const float* __restrict__ dinv,
                                               __half* __restrict__ h1h) {
    __shared__ float w[N_FEAT * HIDDEN];   // 8 KB
    __shared__ float xs[16 * N_FEAT];      // 8 KB
    __shared__ float ds[16];
    int tid  = threadIdx.x;
    int base = blockIdx.x * 16;
    if (tid < 16) ds[tid] = dinv[base + tid];
    const float4* w4 = (const float4*)W1;
    float4*       wd = (float4*)w;
    wd[tid]       = w4[tid];
    wd[256 + tid] = w4[256 + tid];
    const float4* x4 = (const float4*)(x + (long long)base * N_FEAT);
    float4*       xd = (float4*)xs;
    xd[tid]       = x4[tid];
    xd[256 + tid] = x4[256 + tid];
    __syncthreads();
    int n = tid >> 4, c = tid & 15;
    const float* xr = &xs[n * N_FEAT];
    float acc = 0.f;
#pragma unroll
    for (int k = 0; k < N_FEAT; ++k) acc += xr[k] * w[k * HIDDEN + c];
    h1h[(base + n) * HIDDEN + c] = __float2half(acc * ds[n]);
}

#define NT(p) __builtin_nontemporal_load(p)

// Fused: CSR gather of layer-1 aggregation (fp16 table, 3.2MB -> L2-fit,
// 32B/edge) + bias + ReLU + @W2 + dinv scale -> fp16 h2h.
// 16 lanes/node, 16 nodes/block. Software-pipelined: next 8 srcs prefetched
// into registers while current 8 gathers are in flight.
__global__ __launch_bounds__(256) void k_agg1(const int* __restrict__ off,
                                              const int* __restrict__ srcs,
                                              const float* __restrict__ dinv,
                                              const __half* __restrict__ h1h,
                                              const float* __restrict__ b1,
                                              const float* __restrict__ W2,
                                              __half* __restrict__ h2h) {
    __shared__ float r_s[16][17];
    __shared__ float w2s[HIDDEN * N_CLASSES];
    int tid = threadIdx.x;
    if (tid < HIDDEN * N_CLASSES) w2s[tid] = W2[tid];
    int nl = tid >> 4, c = tid & 15;
    int n  = blockIdx.x * 16 + nl;
    int beg = off[n], end = off[n + 1];
    float a0 = __half2float(h1h[n * 16 + c]);   // self-loop
    float a1 = 0.f, a2 = 0.f, a3 = 0.f;
    float a4 = 0.f, a5 = 0.f, a6 = 0.f, a7 = 0.f;
    int j = beg;
    int nfull = (end - beg) >> 3;
    if (nfull > 0) {
        int s0 = NT(&srcs[j]),     s1 = NT(&srcs[j + 1]);
        int s2 = NT(&srcs[j + 2]), s3 = NT(&srcs[j + 3]);
        int s4 = NT(&srcs[j + 4]), s5 = NT(&srcs[j + 5]);
        int s6 = NT(&srcs[j + 6]), s7 = NT(&srcs[j + 7]);
        for (int it = 1; it < nfull; ++it) {
            int t0 = NT(&srcs[j + 8]),  t1 = NT(&srcs[j + 9]);
            int t2 = NT(&srcs[j + 10]), t3 = NT(&srcs[j + 11]);
            int t4 = NT(&srcs[j + 12]), t5 = NT(&srcs[j + 13]);
            int t6 = NT(&srcs[j + 14]), t7 = NT(&srcs[j + 15]);
            a0 += __half2float(h1h[s0 * 16 + c]);
            a1 += __half2float(h1h[s1 * 16 + c]);
            a2 += __half2float(h1h[s2 * 16 + c]);
            a3 += __half2float(h1h[s3 * 16 + c]);
            a4 += __half2float(h1h[s4 * 16 + c]);
            a5 += __half2float(h1h[s5 * 16 + c]);
            a6 += __half2float(h1h[s6 * 16 + c]);
            a7 += __half2float(h1h[s7 * 16 + c]);
            s0 = t0; s1 = t1; s2 = t2; s3 = t3;
            s4 = t4; s5 = t5; s6 = t6; s7 = t7;
            j += 8;
        }
        a0 += __half2float(h1h[s0 * 16 + c]);
        a1 += __half2float(h1h[s1 * 16 + c]);
        a2 += __half2float(h1h[s2 * 16 + c]);
        a3 += __half2float(h1h[s3 * 16 + c]);
        a4 += __half2float(h1h[s4 * 16 + c]);
        a5 += __half2float(h1h[s5 * 16 + c]);
        a6 += __half2float(h1h[s6 * 16 + c]);
        a7 += __half2float(h1h[s7 * 16 + c]);
        j += 8;
    }
    for (; j < end; ++j) a0 += __half2float(h1h[NT(&srcs[j]) * 16 + c]);
    float acc = (((a0 + a1) + (a2 + a3)) + ((a4 + a5) + (a6 + a7)));
    float dn  = dinv[n];
    r_s[nl][c] = fmaxf(dn * acc + b1[c], 0.f);
    __syncthreads();
    float o = 0.f;
    if (c < N_CLASSES) {
#pragma unroll
        for (int k = 0; k < HIDDEN; ++k) o += r_s[nl][k] * w2s[k * N_CLASSES + c];
        o *= dn;
    }
    h2h[n * 16 + c] = __float2half(o);     // c>=10 stores 0
}

// CSR gather of layer-2 aggregation (fp16 table), fused with graph pooling.
__global__ __launch_bounds__(256) void k_agg2p(const int* __restrict__ off,
                                               const int* __restrict__ srcs,
                                               const float* __restrict__ dinv,
                                               const __half* __restrict__ h2h,
                                               const int* __restrict__ batch,
                                               float* __restrict__ pooled) {
    __shared__ float red[16][17];
    int tid = threadIdx.x;
    int nl = tid >> 4, c = tid & 15;
    int nbase = blockIdx.x * 16;
    int n  = nbase + nl;
    int beg = off[n], end = off[n + 1];
    float a0 = __half2float(h2h[n * 16 + c]);   // self-loop
    float a1 = 0.f, a2 = 0.f, a3 = 0.f;
    float a4 = 0.f, a5 = 0.f, a6 = 0.f, a7 = 0.f;
    int j = beg;
    int nfull = (end - beg) >> 3;
    if (nfull > 0) {
        int s0 = NT(&srcs[j]),     s1 = NT(&srcs[j + 1]);
        int s2 = NT(&srcs[j + 2]), s3 = NT(&srcs[j + 3]);
        int s4 = NT(&srcs[j + 4]), s5 = NT(&srcs[j + 5]);
        int s6 = NT(&srcs[j + 6]), s7 = NT(&srcs[j + 7]);
        for (int it = 1; it < nfull; ++it) {
            int t0 = NT(&srcs[j + 8]),  t1 = NT(&srcs[j + 9]);
            int t2 = NT(&srcs[j + 10]), t3 = NT(&srcs[j + 11]);
            int t4 = NT(&srcs[j + 12]), t5 = NT(&srcs[j + 13]);
            int t6 = NT(&srcs[j + 14]), t7 = NT(&srcs[j + 15]);
            a0 += __half2float(h2h[s0 * 16 + c]);
            a1 += __half2float(h2h[s1 * 16 + c]);
            a2 += __half2float(h2h[s2 * 16 + c]);
            a3 += __half2float(h2h[s3 * 16 + c]);
            a4 += __half2float(h2h[s4 * 16 + c]);
            a5 += __half2float(h2h[s5 * 16 + c]);
            a6 += __half2float(h2h[s6 * 16 + c]);
            a7 += __half2float(h2h[s7 * 16 + c]);
            s0 = t0; s1 = t1; s2 = t2; s3 = t3;
            s4 = t4; s5 = t5; s6 = t6; s7 = t7;
            j += 8;
        }
        a0 += __half2float(h2h[s0 * 16 + c]);
        a1 += __half2float(h2h[s1 * 16 + c]);
        a2 += __half2float(h2h[s2 * 16 + c]);
        a3 += __half2float(h2h[s3 * 16 + c]);
        a4 += __half2float(h2h[s4 * 16 + c]);
        a5 += __half2float(h2h[s5 * 16 + c]);
        a6 += __half2float(h2h[s6 * 16 + c]);
        a7 += __half2float(h2h[s7 * 16 + c]);
        j += 8;
    }
    for (; j < end; ++j) a0 += __half2float(h2h[NT(&srcs[j]) * 16 + c]);
    float o = dinv[n] * ((((a0 + a1) + (a2 + a3)) + ((a4 + a5) + (a6 + a7))));

    int g0  = batch[nbase];
    int g15 = batch[nbase + 15];
    if (g0 == g15) {                 // uniform branch: whole block one graph
        red[nl][c] = o;
        __syncthreads();
#pragma unroll
        for (int s = 8; s > 0; s >>= 1) {
            if (nl < s) red[nl][c] += red[nl + s][c];
            __syncthreads();
        }
        if (tid < N_CLASSES) atomicAdd(&pooled[g0 * 16 + tid], red[0][tid]);
    } else {                         // graph boundary inside block (rare)
        if (c < N_CLASSES) atomicAdd(&pooled[batch[n] * 16 + c], o);
    }
}

// one block, one thread per graph: counts via binary search on sorted batch,
// mean + b2, log_softmax -> out.
__global__ __launch_bounds__(64) void k_final(const float* __restrict__ pooled,
                                              const float* __restrict__ b2,
                                              const int* __restrict__ batch,
                                              float* __restrict__ out) {
    int g = threadIdx.x;
    if (g >= N_GRAPHS) return;
    int lo = 0, hi = N_NODES;
    while (lo < hi) { int m = (lo + hi) >> 1; if (batch[m] < g) lo = m + 1; else hi = m; }
    int start = lo;
    lo = 0; hi = N_NODES;
    while (lo < hi) { int m = (lo + hi) >> 1; if (batch[m] < g + 1) lo = m + 1; else hi = m; }
    int cnt = lo - start;

    float v[N_CLASSES];
    if (cnt > 0) {
        float inv = 1.f / (float)cnt;
#pragma unroll
        for (int j = 0; j < N_CLASSES; ++j) v[j] = pooled[g * 16 + j] * inv + b2[j];
    } else {
#pragma unroll
        for (int j = 0; j < N_CLASSES; ++j) v[j] = 0.f;
    }
    float m = v[0];
#pragma unroll
    for (int j = 1; j < N_CLASSES; ++j) m = fmaxf(m, v[j]);
    float l = 0.f;
#pragma unroll
    for (int j = 0; j < N_CLASSES; ++j) l += expf(v[j] - m);
    l = logf(l);
#pragma unroll
    for (int j = 0; j < N_CLASSES; ++j) out[g * N_CLASSES + j] = v[j] - m - l;
}

extern "C" void kernel_launch(void* const* d_in, const int* in_sizes, int n_in,
                              void* d_out, int out_size, void* d_ws, size_t ws_size,
                              hipStream_t stream) {
    const float* x     = (const float*)d_in[0];
    const int*   edge  = (const int*)d_in[1];   // [2, E]
    const int*   batch = (const int*)d_in[2];
    const float* W1    = (const float*)d_in[3];
    const float* b1    = (const float*)d_in[4];
    const float* W2    = (const float*)d_in[5];
    const float* b2    = (const float*)d_in[6];
    float* out = (float*)d_out;
    float* ws  = (float*)d_ws;

    int*    gcur   = (int*)ws;                  // [0, 512)
    int*    bbase  = (int*)(ws + 512);          // [512, 1024)
    float*  pooled = ws + 1024;                 // [1024, 2048)
    float*  dinv   = ws + 2048;                 // [2048, 102048)
    int*    off    = (int*)(ws + 102048);       // 100001 used
    int*    srcs   = (int*)(ws + 202080);       // 3.2M
    int*    stage  = (int*)(ws + 3402080);      // 391*9216
    __half* h1h    = (__half*)(ws + 3402080);   // overlays stage (dead after binB)
    __half* h2h    = (__half*)(ws + 4202080);

    const int* srcp = edge;
    const int* dstp = edge + N_EDGES;

    k_ginit<<<1, 512, 0, stream>>>(gcur, pooled);
    k_binA<<<BINA_BLOCKS, 1024, 0, stream>>>(srcp, dstp, gcur, stage);
    k_bscan<<<1, 512, 0, stream>>>(gcur, bbase, off);
    k_binB<<<NBUCK, 256, 0, stream>>>(gcur, bbase, stage, off, dinv, srcs);
    k_gemm1<<<N_NODES / 16, 256, 0, stream>>>(x, W1, dinv, h1h);
    k_agg1<<<N_NODES / 16, 256, 0, stream>>>(off, srcs, dinv, h1h, b1, W2, h2h);
    k_agg2p<<<N_NODES / 16, 256, 0, stream>>>(off, srcs, dinv, h2h, batch, pooled);
    k_final<<<1, 64, 0, stream>>>(pooled, b2, batch, out);
}

// Round 8
// 249.066 us; speedup vs baseline: 1.4861x; 1.0824x over previous
//
#include <hip/hip_runtime.h>
#include <hip/hip_fp16.h>

#define N_NODES   100000
#define N_EDGES   3200000
#define N_FEAT    128
#define HIDDEN    16
#define N_CLASSES 10
#define N_GRAPHS  64

#define NBUCK     391          // ceil(N_NODES/256), bucket = dst >> 8
#define CAP       9216         // staging capacity per bucket (mean 8192, +11 sigma)
#define BINA_EPB  16384        // edges per block in k_binA (1024 thr x 16)
#define BINA_BLOCKS ((N_EDGES + BINA_EPB - 1) / BINA_EPB)   // 196

// Workspace layout (4-byte units):
//   gcur   : [0,        512)       int, per-bucket staging cursor
//   bbase  : [512,      1024)      int, per-bucket CSR base
//   pooled : [1024,     2048)      float [64][16], zeroed each launch
//   dinv   : [2048,     102048)    float
//   off    : [102048,   202080)    int (100001 used)
//   srcs   : [202080,   3402080)   int, CSR by dst
//   stage  : [3402080,  7005536)   int, 391*9216 packed (src<<8 | dst&255)
//   h1h    : [3402080,  4202080)   __half [N][16] (x@W1)*dinv  (overlays stage)
//   h2h    : [4202080,  5002080)   __half [N][16] layer-2 feats, c>=10 zero
// total ~28.0 MB

__global__ __launch_bounds__(512) void k_ginit(int* __restrict__ gcur,
                                               float* __restrict__ pooled) {
    int t = threadIdx.x;
    if (t < NBUCK) gcur[t] = t * CAP;
    pooled[t] = 0.f;
    pooled[t + 512] = 0.f;
}

// Bin edges by dst>>8 into per-bucket staging. Per block: LDS histogram of
// 16384 edges -> ONE global atomic per bucket reserves a contiguous run
// (~42 edges = 168B) -> LDS-cursor scatter. Edges cached in registers.
__global__ __launch_bounds__(1024) void k_binA(const int* __restrict__ src,
                                               const int* __restrict__ dst,
                                               int* __restrict__ gcur,
                                               int* __restrict__ stage) {
    __shared__ int hist[NBUCK];
    __shared__ int curb[NBUCK];
    int tid = threadIdx.x;
    long long base = (long long)blockIdx.x * BINA_EPB;
    for (int t = tid; t < NBUCK; t += 1024) hist[t] = 0;
    __syncthreads();
    int se[16], de[16];
#pragma unroll
    for (int i = 0; i < 16; ++i) {
        long long e = base + i * 1024 + tid;
        if (e < N_EDGES) {
            se[i] = src[e];
            de[i] = dst[e];
            atomicAdd(&hist[de[i] >> 8], 1);
        } else {
            de[i] = -1;
        }
    }
    __syncthreads();
    for (int t = tid; t < NBUCK; t += 1024) {
        int h = hist[t];
        curb[t] = h ? atomicAdd(&gcur[t], h) : 0;
    }
    __syncthreads();
#pragma unroll
    for (int i = 0; i < 16; ++i) {
        if (de[i] >= 0) {
            int b = de[i] >> 8;
            int p = atomicAdd(&curb[b], 1);
            stage[p] = (se[i] << 8) | (de[i] & 255);
        }
    }
}

// Exclusive scan of bucket counts -> per-bucket CSR base.
__global__ __launch_bounds__(512) void k_bscan(const int* __restrict__ gcur,
                                               int* __restrict__ bbase,
                                               int* __restrict__ off) {
    __shared__ int s[512];
    int t = threadIdx.x;
    int c = (t < NBUCK) ? (gcur[t] - t * CAP) : 0;
    s[t] = c;
    __syncthreads();
    for (int o = 1; o < 512; o <<= 1) {
        int a = (t >= o) ? s[t - o] : 0;
        __syncthreads();
        s[t] += a;
        __syncthreads();
    }
    if (t < NBUCK) bbase[t] = s[t] - c;
    if (t == 0) off[N_NODES] = N_EDGES;
}

// One block per bucket: per-node histogram + scan -> off/dinv, then place
// each staged edge at its final CSR slot.
__global__ __launch_bounds__(256) void k_binB(const int* __restrict__ gcur,
                                              const int* __restrict__ bbase,
                                              const int* __restrict__ stage,
                                              int* __restrict__ off,
                                              float* __restrict__ dinv,
                                              int* __restrict__ srcs) {
    __shared__ int hist[256];
    __shared__ int excl[256];
    int b = blockIdx.x, t = threadIdx.x;
    int cnt   = gcur[b] - b * CAP;
    int sbase = b * CAP;
    int cbase = bbase[b];
    hist[t] = 0;
    __syncthreads();
    for (int i = t; i < cnt; i += 256) {
        int v = stage[sbase + i];
        atomicAdd(&hist[v & 255], 1);
    }
    __syncthreads();
    int c = hist[t];
    excl[t] = c;
    __syncthreads();
    for (int o = 1; o < 256; o <<= 1) {
        int a = (t >= o) ? excl[t - o] : 0;
        __syncthreads();
        excl[t] += a;
        __syncthreads();
    }
    int ex = excl[t] - c;
    int node = b * 256 + t;
    if (node < N_NODES) {
        off[node]  = cbase + ex;
        dinv[node] = rsqrtf((float)c + 1.0f);
    }
    __syncthreads();
    hist[t] = ex;          // reuse as per-node cursor
    __syncthreads();
    for (int i = t; i < cnt; i += 256) {
        int v = stage[sbase + i];
        int p = cbase + atomicAdd(&hist[v & 255], 1);
        srcs[p] = v >> 8;
    }
}

// 16 nodes per block: h1h[n][c] = fp16((x[n] @ W1)[c] * dinv[n])
__global__ __launch_bounds__(256) void k_gemm1(const float* __restrict__ x,
                                               const float* __restrict__ W1,
                                               const float* __restrict__ dinv,
                                               __half* __restrict__ h1h) {
    __shared__ float w[N_FEAT * HIDDEN];   // 8 KB
    __shared__ float xs[16 * N_FEAT];      // 8 KB
    __shared__ float ds[16];
    int tid  = threadIdx.x;
    int base = blockIdx.x * 16;
    if (tid < 16) ds[tid] = dinv[base + tid];
    const float4* w4 = (const float4*)W1;
    float4*       wd = (float4*)w;
    wd[tid]       = w4[tid];
    wd[256 + tid] = w4[256 + tid];
    const float4* x4 = (const float4*)(x + (long long)base * N_FEAT);
    float4*       xd = (float4*)xs;
    xd[tid]       = x4[tid];
    xd[256 + tid] = x4[256 + tid];
    __syncthreads();
    int n = tid >> 4, c = tid & 15;
    const float* xr = &xs[n * N_FEAT];
    float acc = 0.f;
#pragma unroll
    for (int k = 0; k < N_FEAT; ++k) acc += xr[k] * w[k * HIDDEN + c];
    h1h[(base + n) * HIDDEN + c] = __float2half(acc * ds[n]);
}

#define NT(p) __builtin_nontemporal_load(p)

// Edge gather core: 16-lane node group = 8 edge-slots x 2 halves.
// Per round the group covers 8 edges; each lane loads 16B (8 halves =
// channels h*8..h*8+7) of its edge. acc[8] per lane; 2-round software
// pipeline keeps 2 gathers + 2 src loads in flight per lane.
#define GATHER_DEF(TBL)                                                       \
    float acc[8];                                                             \
    _Pragma("unroll") for (int q = 0; q < 8; ++q) acc[q] = 0.f;               \
    {                                                                         \
        int ne = end - beg;                                                   \
        int nr = ne >> 3;                                                     \
        int j  = beg + k;                                                     \
        int npair = nr >> 1;                                                  \
        if (npair > 0) {                                                      \
            int sA = NT(&srcs[j]), sB = NT(&srcs[j + 8]);                     \
            for (int p = 1; p < npair; ++p) {                                 \
                int sC = NT(&srcs[j + 16]), sD = NT(&srcs[j + 24]);           \
                GACC(TBL, sA); GACC(TBL, sB);                                 \
                sA = sC; sB = sD; j += 16;                                    \
            }                                                                 \
            GACC(TBL, sA); GACC(TBL, sB); j += 16;                            \
        }                                                                     \
        if (nr & 1) { int sA = NT(&srcs[j]); GACC(TBL, sA); j += 8; }         \
        if (k < (ne & 7)) { int sA = NT(&srcs[j]); GACC(TBL, sA); }           \
    }                                                                         \
    _Pragma("unroll") for (int m = 2; m <= 8; m <<= 1) {                      \
        _Pragma("unroll") for (int q = 0; q < 8; ++q)                         \
            acc[q] += __shfl_xor(acc[q], m, 64);                              \
    }

#define GACC(TBL, S) {                                                        \
    float4 g_ = *(const float4*)(&TBL[(S) * 16 + h * 8]);                     \
    const __half2* hp_ = (const __half2*)&g_;                                 \
    float2 v0_ = __half22float2(hp_[0]);                                      \
    float2 v1_ = __half22float2(hp_[1]);                                      \
    float2 v2_ = __half22float2(hp_[2]);                                      \
    float2 v3_ = __half22float2(hp_[3]);                                      \
    acc[0] += v0_.x; acc[1] += v0_.y; acc[2] += v1_.x; acc[3] += v1_.y;       \
    acc[4] += v2_.x; acc[5] += v2_.y; acc[6] += v3_.x; acc[7] += v3_.y; }

// Fused: CSR gather of layer-1 aggregation + bias + ReLU + @W2 + dinv scale.
__global__ __launch_bounds__(256) void k_agg1(const int* __restrict__ off,
                                              const int* __restrict__ srcs,
                                              const float* __restrict__ dinv,
                                              const __half* __restrict__ h1h,
                                              const float* __restrict__ b1,
                                              const float* __restrict__ W2,
                                              __half* __restrict__ h2h) {
    __shared__ float r_s[16][17];
    __shared__ float w2s[HIDDEN * N_CLASSES];
    int tid = threadIdx.x;
    if (tid < HIDDEN * N_CLASSES) w2s[tid] = W2[tid];
    int nl = tid >> 4, l = tid & 15, k = l >> 1, h = l & 1;
    int n  = blockIdx.x * 16 + nl;
    int beg = off[n], end = off[n + 1];
    GATHER_DEF(h1h)
    if (l < 2) {
#pragma unroll
        for (int q = 0; q < 8; ++q) r_s[nl][h * 8 + q] = acc[q];
    }
    __syncthreads();
    float dn   = dinv[n];
    float self = __half2float(h1h[n * 16 + l]);
    float val  = fmaxf(dn * (r_s[nl][l] + self) + b1[l], 0.f);
    __syncthreads();
    r_s[nl][l] = val;
    __syncthreads();
    float o = 0.f;
    if (l < N_CLASSES) {
#pragma unroll
        for (int q = 0; q < HIDDEN; ++q) o += r_s[nl][q] * w2s[q * N_CLASSES + l];
        o *= dn;
    }
    h2h[n * 16 + l] = __float2half(o);     // l>=10 stores 0
}

// CSR gather of layer-2 aggregation, fused with graph pooling.
__global__ __launch_bounds__(256) void k_agg2p(const int* __restrict__ off,
                                               const int* __restrict__ srcs,
                                               const float* __restrict__ dinv,
                                               const __half* __restrict__ h2h,
                                               const int* __restrict__ batch,
                                               float* __restrict__ pooled) {
    __shared__ float red[16][17];
    int tid = threadIdx.x;
    int nl = tid >> 4, l = tid & 15, k = l >> 1, h = l & 1;
    int nbase = blockIdx.x * 16;
    int n  = nbase + nl;
    int beg = off[n], end = off[n + 1];
    GATHER_DEF(h2h)
    if (l < 2) {
#pragma unroll
        for (int q = 0; q < 8; ++q) red[nl][h * 8 + q] = acc[q];
    }
    __syncthreads();
    float self = __half2float(h2h[n * 16 + l]);
    float o = dinv[n] * (red[nl][l] + self);   // l>=10: table is 0 -> o=0
    __syncthreads();

    int g0  = batch[nbase];
    int g15 = batch[nbase + 15];
    if (g0 == g15) {                 // uniform branch: whole block one graph
        red[nl][l] = o;
        __syncthreads();
#pragma unroll
        for (int s = 8; s > 0; s >>= 1) {
            if (nl < s) red[nl][l] += red[nl + s][l];
            __syncthreads();
        }
        if (tid < N_CLASSES) atomicAdd(&pooled[g0 * 16 + tid], red[0][tid]);
    } else {                         // graph boundary inside block (rare)
        if (l < N_CLASSES) atomicAdd(&pooled[batch[n] * 16 + l], o);
    }
}

// one block, one thread per graph: counts via binary search on sorted batch,
// mean + b2, log_softmax -> out.
__global__ __launch_bounds__(64) void k_final(const float* __restrict__ pooled,
                                              const float* __restrict__ b2,
                                              const int* __restrict__ batch,
                                              float* __restrict__ out) {
    int g = threadIdx.x;
    if (g >= N_GRAPHS) return;
    int lo = 0, hi = N_NODES;
    while (lo < hi) { int m = (lo + hi) >> 1; if (batch[m] < g) lo = m + 1; else hi = m; }
    int start = lo;
    lo = 0; hi = N_NODES;
    while (lo < hi) { int m = (lo + hi) >> 1; if (batch[m] < g + 1) lo = m + 1; else hi = m; }
    int cnt = lo - start;

    float v[N_CLASSES];
    if (cnt > 0) {
        float inv = 1.f / (float)cnt;
#pragma unroll
        for (int j = 0; j < N_CLASSES; ++j) v[j] = pooled[g * 16 + j] * inv + b2[j];
    } else {
#pragma unroll
        for (int j = 0; j < N_CLASSES; ++j) v[j] = 0.f;
    }
    float m = v[0];
#pragma unroll
    for (int j = 1; j < N_CLASSES; ++j) m = fmaxf(m, v[j]);
    float l = 0.f;
#pragma unroll
    for (int j = 0; j < N_CLASSES; ++j) l += expf(v[j] - m);
    l = logf(l);
#pragma unroll
    for (int j = 0; j < N_CLASSES; ++j) out[g * N_CLASSES + j] = v[j] - m - l;
}

extern "C" void kernel_launch(void* const* d_in, const int* in_sizes, int n_in,
                              void* d_out, int out_size, void* d_ws, size_t ws_size,
                              hipStream_t stream) {
    const float* x     = (const float*)d_in[0];
    const int*   edge  = (const int*)d_in[1];   // [2, E]
    const int*   batch = (const int*)d_in[2];
    const float* W1    = (const float*)d_in[3];
    const float* b1    = (const float*)d_in[4];
    const float* W2    = (const float*)d_in[5];
    const float* b2    = (const float*)d_in[6];
    float* out = (float*)d_out;
    float* ws  = (float*)d_ws;

    int*    gcur   = (int*)ws;                  // [0, 512)
    int*    bbase  = (int*)(ws + 512);          // [512, 1024)
    float*  pooled = ws + 1024;                 // [1024, 2048)
    float*  dinv   = ws + 2048;                 // [2048, 102048)
    int*    off    = (int*)(ws + 102048);       // 100001 used
    int*    srcs   = (int*)(ws + 202080);       // 3.2M
    int*    stage  = (int*)(ws + 3402080);      // 391*9216
    __half* h1h    = (__half*)(ws + 3402080);   // overlays stage (dead after binB)
    __half* h2h    = (__half*)(ws + 4202080);

    const int* srcp = edge;
    const int* dstp = edge + N_EDGES;

    k_ginit<<<1, 512, 0, stream>>>(gcur, pooled);
    k_binA<<<BINA_BLOCKS, 1024, 0, stream>>>(srcp, dstp, gcur, stage);
    k_bscan<<<1, 512, 0, stream>>>(gcur, bbase, off);
    k_binB<<<NBUCK, 256, 0, stream>>>(gcur, bbase, stage, off, dinv, srcs);
    k_gemm1<<<N_NODES / 16, 256, 0, stream>>>(x, W1, dinv, h1h);
    k_agg1<<<N_NODES / 16, 256, 0, stream>>>(off, srcs, dinv, h1h, b1, W2, h2h);
    k_agg2p<<<N_NODES / 16, 256, 0, stream>>>(off, srcs, dinv, h2h, batch, pooled);
    k_final<<<1, 64, 0, stream>>>(pooled, b2, batch, out);
}

// Round 9
// 238.628 us; speedup vs baseline: 1.5511x; 1.0437x over previous
//
#include <hip/hip_runtime.h>
#include <hip/hip_fp16.h>

#define N_NODES   100000
#define N_EDGES   3200000
#define N_FEAT    128
#define HIDDEN    16
#define N_CLASSES 10
#define N_GRAPHS  64

#define NBUCK     391          // ceil(N_NODES/256), bucket = dst >> 8
#define CAP       9216         // staging capacity per bucket (mean 8192, +11 sigma)
#define BINA_EPB  16384        // edges per block in k_binA (1024 thr x 16)
#define BINA_BLOCKS ((N_EDGES + BINA_EPB - 1) / BINA_EPB)   // 196

// Workspace layout (4-byte units):
//   gcur   : [0,        512)       int, per-bucket staging cursor
//   pooled : [512,      1536)      float [64][16], zeroed each launch
//   dinv   : [1536,     101536)    float
//   be     : [101536,   301536)    int2 per node: (beg, end) into srcs
//   srcs   : [301536,   3904992)   int, CSR by dst at fixed base b*CAP
//   stage  : [3904992,  7508448)   int, 391*9216 packed (src<<8 | dst&255)
//   h1h    : [3904992,  4704992)   __half [N][16] (x@W1)*dinv  (overlays stage)
//   h2h    : [4704992,  5504992)   __half [N][16] layer-2 feats, c>=10 zero
// total ~30.0 MB

__global__ __launch_bounds__(512) void k_ginit(int* __restrict__ gcur,
                                               float* __restrict__ pooled) {
    int t = threadIdx.x;
    if (t < NBUCK) gcur[t] = t * CAP;
    pooled[t] = 0.f;
    pooled[t + 512] = 0.f;
}

// Bin edges by dst>>8 into per-bucket staging. Per block: LDS histogram of
// 16384 edges -> ONE global atomic per bucket reserves a contiguous run
// (~42 edges = 168B) -> LDS-cursor scatter. Edges cached in registers.
__global__ __launch_bounds__(1024) void k_binA(const int* __restrict__ src,
                                               const int* __restrict__ dst,
                                               int* __restrict__ gcur,
                                               int* __restrict__ stage) {
    __shared__ int hist[NBUCK];
    __shared__ int curb[NBUCK];
    int tid = threadIdx.x;
    long long base = (long long)blockIdx.x * BINA_EPB;
    for (int t = tid; t < NBUCK; t += 1024) hist[t] = 0;
    __syncthreads();
    int se[16], de[16];
#pragma unroll
    for (int i = 0; i < 16; ++i) {
        long long e = base + i * 1024 + tid;
        if (e < N_EDGES) {
            se[i] = src[e];
            de[i] = dst[e];
            atomicAdd(&hist[de[i] >> 8], 1);
        } else {
            de[i] = -1;
        }
    }
    __syncthreads();
    for (int t = tid; t < NBUCK; t += 1024) {
        int h = hist[t];
        curb[t] = h ? atomicAdd(&gcur[t], h) : 0;
    }
    __syncthreads();
#pragma unroll
    for (int i = 0; i < 16; ++i) {
        if (de[i] >= 0) {
            int b = de[i] >> 8;
            int p = atomicAdd(&curb[b], 1);
            stage[p] = (se[i] << 8) | (de[i] & 255);
        }
    }
}

// One block (512 thr) per bucket: int4-vectorized per-node histogram + scan
// -> be/dinv, then int4-vectorized placement into fixed-base CSR slots
// (bucket b owns srcs[b*CAP .. b*CAP+cnt)). No global scan needed.
__global__ __launch_bounds__(512) void k_binB(const int* __restrict__ gcur,
                                              const int* __restrict__ stage,
                                              int2* __restrict__ be,
                                              float* __restrict__ dinv,
                                              int* __restrict__ srcs) {
    __shared__ int hist[256];
    __shared__ int excl[256];
    int b = blockIdx.x, tid = threadIdx.x;
    int cnt   = gcur[b] - b * CAP;
    int sbase = b * CAP;
    if (tid < 256) hist[tid] = 0;
    __syncthreads();
    int nvec = cnt >> 2;                   // full int4 groups
    for (int i = tid; i < nvec; i += 512) {
        int4 v = *(const int4*)&stage[sbase + i * 4];
        atomicAdd(&hist[v.x & 255], 1);
        atomicAdd(&hist[v.y & 255], 1);
        atomicAdd(&hist[v.z & 255], 1);
        atomicAdd(&hist[v.w & 255], 1);
    }
    if (tid < (cnt & 3)) {                 // tail
        int v = stage[sbase + (nvec << 2) + tid];
        atomicAdd(&hist[v & 255], 1);
    }
    __syncthreads();
    int c = 0, ex = 0;
    if (tid < 256) {
        c = hist[tid];
        excl[tid] = c;
    }
    __syncthreads();
    for (int o = 1; o < 256; o <<= 1) {
        int a = 0;
        if (tid < 256 && tid >= o) a = excl[tid - o];
        __syncthreads();
        if (tid < 256) excl[tid] += a;
        __syncthreads();
    }
    if (tid < 256) {
        ex = excl[tid] - c;
        int node = b * 256 + tid;
        if (node < N_NODES) {
            be[node]   = make_int2(sbase + ex, sbase + ex + c);
            dinv[node] = rsqrtf((float)c + 1.0f);
        }
    }
    __syncthreads();
    if (tid < 256) hist[tid] = ex;         // reuse as per-node cursor
    __syncthreads();
    for (int i = tid; i < nvec; i += 512) {
        int4 v = *(const int4*)&stage[sbase + i * 4];
        int p0 = atomicAdd(&hist[v.x & 255], 1);
        int p1 = atomicAdd(&hist[v.y & 255], 1);
        int p2 = atomicAdd(&hist[v.z & 255], 1);
        int p3 = atomicAdd(&hist[v.w & 255], 1);
        srcs[sbase + p0] = v.x >> 8;
        srcs[sbase + p1] = v.y >> 8;
        srcs[sbase + p2] = v.z >> 8;
        srcs[sbase + p3] = v.w >> 8;
    }
    if (tid < (cnt & 3)) {
        int v = stage[sbase + (nvec << 2) + tid];
        int p = atomicAdd(&hist[v & 255], 1);
        srcs[sbase + p] = v >> 8;
    }
}

// 16 nodes per block: h1h[n][c] = fp16((x[n] @ W1)[c] * dinv[n])
__global__ __launch_bounds__(256) void k_gemm1(const float* __restrict__ x,
                                               const float* __restrict__ W1,
                                               const float* __restrict__ dinv,
                                               __half* __restrict__ h1h) {
    __shared__ float w[N_FEAT * HIDDEN];   // 8 KB
    __shared__ float xs[16 * N_FEAT];      // 8 KB
    __shared__ float ds[16];
    int tid  = threadIdx.x;
    int base = blockIdx.x * 16;
    if (tid < 16) ds[tid] = dinv[base + tid];
    const float4* w4 = (const float4*)W1;
    float4*       wd = (float4*)w;
    wd[tid]       = w4[tid];
    wd[256 + tid] = w4[256 + tid];
    const float4* x4 = (const float4*)(x + (long long)base * N_FEAT);
    float4*       xd = (float4*)xs;
    xd[tid]       = x4[tid];
    xd[256 + tid] = x4[256 + tid];
    __syncthreads();
    int n = tid >> 4, c = tid & 15;
    const float* xr = &xs[n * N_FEAT];
    float acc = 0.f;
#pragma unroll
    for (int k = 0; k < N_FEAT; ++k) acc += xr[k] * w[k * HIDDEN + c];
    h1h[(base + n) * HIDDEN + c] = __float2half(acc * ds[n]);
}

#define NT(p) __builtin_nontemporal_load(p)

// Edge gather core: 16-lane node group = 8 edge-slots x 2 halves.
// Per round the group covers 8 edges; each lane loads 16B (8 halves =
// channels h*8..h*8+7) of its edge. acc[8] per lane; 2-round software
// pipeline keeps 2 gathers + 2 src loads in flight per lane.
#define GATHER_DEF(TBL)                                                       \
    float acc[8];                                                             \
    _Pragma("unroll") for (int q = 0; q < 8; ++q) acc[q] = 0.f;               \
    {                                                                         \
        int ne = end - beg;                                                   \
        int nr = ne >> 3;                                                     \
        int j  = beg + k;                                                     \
        int npair = nr >> 1;                                                  \
        if (npair > 0) {                                                      \
            int sA = NT(&srcs[j]), sB = NT(&srcs[j + 8]);                     \
            for (int p = 1; p < npair; ++p) {                                 \
                int sC = NT(&srcs[j + 16]), sD = NT(&srcs[j + 24]);           \
                GACC(TBL, sA); GACC(TBL, sB);                                 \
                sA = sC; sB = sD; j += 16;                                    \
            }                                                                 \
            GACC(TBL, sA); GACC(TBL, sB); j += 16;                            \
        }                                                                     \
        if (nr & 1) { int sA = NT(&srcs[j]); GACC(TBL, sA); j += 8; }         \
        if (k < (ne & 7)) { int sA = NT(&srcs[j]); GACC(TBL, sA); }           \
    }                                                                         \
    _Pragma("unroll") for (int m = 2; m <= 8; m <<= 1) {                      \
        _Pragma("unroll") for (int q = 0; q < 8; ++q)                         \
            acc[q] += __shfl_xor(acc[q], m, 64);                              \
    }

#define GACC(TBL, S) {                                                        \
    float4 g_ = *(const float4*)(&TBL[(S) * 16 + h * 8]);                     \
    const __half2* hp_ = (const __half2*)&g_;                                 \
    float2 v0_ = __half22float2(hp_[0]);                                      \
    float2 v1_ = __half22float2(hp_[1]);                                      \
    float2 v2_ = __half22float2(hp_[2]);                                      \
    float2 v3_ = __half22float2(hp_[3]);                                      \
    acc[0] += v0_.x; acc[1] += v0_.y; acc[2] += v1_.x; acc[3] += v1_.y;       \
    acc[4] += v2_.x; acc[5] += v2_.y; acc[6] += v3_.x; acc[7] += v3_.y; }

// Fused: CSR gather of layer-1 aggregation + bias + ReLU + @W2 + dinv scale.
__global__ __launch_bounds__(256) void k_agg1(const int2* __restrict__ be,
                                              const int* __restrict__ srcs,
                                              const float* __restrict__ dinv,
                                              const __half* __restrict__ h1h,
                                              const float* __restrict__ b1,
                                              const float* __restrict__ W2,
                                              __half* __restrict__ h2h) {
    __shared__ float r_s[16][17];
    __shared__ float w2s[HIDDEN * N_CLASSES];
    int tid = threadIdx.x;
    if (tid < HIDDEN * N_CLASSES) w2s[tid] = W2[tid];
    int nl = tid >> 4, l = tid & 15, k = l >> 1, h = l & 1;
    int n  = blockIdx.x * 16 + nl;
    int2 bn = be[n];
    int beg = bn.x, end = bn.y;
    GATHER_DEF(h1h)
    if (l < 2) {
#pragma unroll
        for (int q = 0; q < 8; ++q) r_s[nl][h * 8 + q] = acc[q];
    }
    __syncthreads();
    float dn   = dinv[n];
    float self = __half2float(h1h[n * 16 + l]);
    float val  = fmaxf(dn * (r_s[nl][l] + self) + b1[l], 0.f);
    __syncthreads();
    r_s[nl][l] = val;
    __syncthreads();
    float o = 0.f;
    if (l < N_CLASSES) {
#pragma unroll
        for (int q = 0; q < HIDDEN; ++q) o += r_s[nl][q] * w2s[q * N_CLASSES + l];
        o *= dn;
    }
    h2h[n * 16 + l] = __float2half(o);     // l>=10 stores 0
}

// CSR gather of layer-2 aggregation, fused with graph pooling.
__global__ __launch_bounds__(256) void k_agg2p(const int2* __restrict__ be,
                                               const int* __restrict__ srcs,
                                               const float* __restrict__ dinv,
                                               const __half* __restrict__ h2h,
                                               const int* __restrict__ batch,
                                               float* __restrict__ pooled) {
    __shared__ float red[16][17];
    int tid = threadIdx.x;
    int nl = tid >> 4, l = tid & 15, k = l >> 1, h = l & 1;
    int nbase = blockIdx.x * 16;
    int n  = nbase + nl;
    int2 bn = be[n];
    int beg = bn.x, end = bn.y;
    GATHER_DEF(h2h)
    if (l < 2) {
#pragma unroll
        for (int q = 0; q < 8; ++q) red[nl][h * 8 + q] = acc[q];
    }
    __syncthreads();
    float self = __half2float(h2h[n * 16 + l]);
    float o = dinv[n] * (red[nl][l] + self);   // l>=10: table is 0 -> o=0
    __syncthreads();

    int g0  = batch[nbase];
    int g15 = batch[nbase + 15];
    if (g0 == g15) {                 // uniform branch: whole block one graph
        red[nl][l] = o;
        __syncthreads();
#pragma unroll
        for (int s = 8; s > 0; s >>= 1) {
            if (nl < s) red[nl][l] += red[nl + s][l];
            __syncthreads();
        }
        if (tid < N_CLASSES) atomicAdd(&pooled[g0 * 16 + tid], red[0][tid]);
    } else {                         // graph boundary inside block (rare)
        if (l < N_CLASSES) atomicAdd(&pooled[batch[n] * 16 + l], o);
    }
}

// one block, one thread per graph: counts via binary search on sorted batch,
// mean + b2, log_softmax -> out.
__global__ __launch_bounds__(64) void k_final(const float* __restrict__ pooled,
                                              const float* __restrict__ b2,
                                              const int* __restrict__ batch,
                                              float* __restrict__ out) {
    int g = threadIdx.x;
    if (g >= N_GRAPHS) return;
    int lo = 0, hi = N_NODES;
    while (lo < hi) { int m = (lo + hi) >> 1; if (batch[m] < g) lo = m + 1; else hi = m; }
    int start = lo;
    lo = 0; hi = N_NODES;
    while (lo < hi) { int m = (lo + hi) >> 1; if (batch[m] < g + 1) lo = m + 1; else hi = m; }
    int cnt = lo - start;

    float v[N_CLASSES];
    if (cnt > 0) {
        float inv = 1.f / (float)cnt;
#pragma unroll
        for (int j = 0; j < N_CLASSES; ++j) v[j] = pooled[g * 16 + j] * inv + b2[j];
    } else {
#pragma unroll
        for (int j = 0; j < N_CLASSES; ++j) v[j] = 0.f;
    }
    float m = v[0];
#pragma unroll
    for (int j = 1; j < N_CLASSES; ++j) m = fmaxf(m, v[j]);
    float l = 0.f;
#pragma unroll
    for (int j = 0; j < N_CLASSES; ++j) l += expf(v[j] - m);
    l = logf(l);
#pragma unroll
    for (int j = 0; j < N_CLASSES; ++j) out[g * N_CLASSES + j] = v[j] - m - l;
}

extern "C" void kernel_launch(void* const* d_in, const int* in_sizes, int n_in,
                              void* d_out, int out_size, void* d_ws, size_t ws_size,
                              hipStream_t stream) {
    const float* x     = (const float*)d_in[0];
    const int*   edge  = (const int*)d_in[1];   // [2, E]
    const int*   batch = (const int*)d_in[2];
    const float* W1    = (const float*)d_in[3];
    const float* b1    = (const float*)d_in[4];
    const float* W2    = (const float*)d_in[5];
    const float* b2    = (const float*)d_in[6];
    float* out = (float*)d_out;
    float* ws  = (float*)d_ws;

    int*    gcur   = (int*)ws;                  // [0, 512)
    float*  pooled = ws + 512;                  // [512, 1536)
    float*  dinv   = ws + 1536;                 // [1536, 101536)
    int2*   be     = (int2*)(ws + 101536);      // [101536, 301536)
    int*    srcs   = (int*)(ws + 301536);       // NBUCK*CAP, fixed-base CSR
    int*    stage  = (int*)(ws + 3904992);      // 391*9216
    __half* h1h    = (__half*)(ws + 3904992);   // overlays stage (dead after binB)
    __half* h2h    = (__half*)(ws + 4704992);

    const int* srcp = edge;
    const int* dstp = edge + N_EDGES;

    k_ginit<<<1, 512, 0, stream>>>(gcur, pooled);
    k_binA<<<BINA_BLOCKS, 1024, 0, stream>>>(srcp, dstp, gcur, stage);
    k_binB<<<NBUCK, 512, 0, stream>>>(gcur, stage, be, dinv, srcs);
    k_gemm1<<<N_NODES / 16, 256, 0, stream>>>(x, W1, dinv, h1h);
    k_agg1<<<N_NODES / 16, 256, 0, stream>>>(be, srcs, dinv, h1h, b1, W2, h2h);
    k_agg2p<<<N_NODES / 16, 256, 0, stream>>>(be, srcs, dinv, h2h, batch, pooled);
    k_final<<<1, 64, 0, stream>>>(pooled, b2, batch, out);
}